// Round 10
// baseline (383.755 us; speedup 1.0000x reference)
//
#include <hip/hip_runtime.h>

#define NN 50000
#define NE 800000
#define NG 512
#define INDIM 100
#define OUTD 24
#define NB_SCAN 196  // ceil(50000/256)
#define LROW 72      // padded LDS row (ushorts): 144B stride, 16B-aligned
#define XROW 136     // padded LDS row for pre0 x-tile (ushorts)

typedef __attribute__((ext_vector_type(8))) short short8;
typedef __attribute__((ext_vector_type(4))) float floatx4;

// bf16 raw-bits helpers (RNE pack)
__device__ inline float bf2f(unsigned short u) {
    unsigned v = (unsigned)u << 16;
    float f;
    __builtin_memcpy(&f, &v, 4);
    return f;
}
__device__ inline unsigned short f2bf(float f) {
    unsigned u;
    __builtin_memcpy(&u, &f, 4);
    u += 0x7fffu + ((u >> 16) & 1u);  // round-to-nearest-even
    return (unsigned short)(u >> 16);
}

// ---------------- CSR build ----------------

__global__ __launch_bounds__(256) void k_hist(const int* __restrict__ ei, int* __restrict__ deg) {
    unsigned e = blockIdx.x * 256u + threadIdx.x;
    if (e >= NE) return;
    atomicAdd(&deg[ei[NE + e]], 1);
}

__global__ __launch_bounds__(256) void k_scan1(const int* __restrict__ deg,
                                               int* __restrict__ rowptr,
                                               int* __restrict__ bsums) {
    __shared__ int s[256];
    int t = threadIdx.x;
    int i = blockIdx.x * 256 + t;
    int v = (i < NN) ? deg[i] : 0;
    s[t] = v;
    __syncthreads();
    for (int off = 1; off < 256; off <<= 1) {
        int u = (t >= off) ? s[t - off] : 0;
        __syncthreads();
        s[t] += u;
        __syncthreads();
    }
    if (i < NN) rowptr[i] = s[t] - v;
    if (t == 255) bsums[blockIdx.x] = s[255];
}

__global__ __launch_bounds__(256) void k_scan2(const int* __restrict__ bsums,
                                               int* __restrict__ boffs) {
    __shared__ int s[256];
    int t = threadIdx.x;
    int v = (t < NB_SCAN) ? bsums[t] : 0;
    s[t] = v;
    __syncthreads();
    for (int off = 1; off < 256; off <<= 1) {
        int u = (t >= off) ? s[t - off] : 0;
        __syncthreads();
        s[t] += u;
        __syncthreads();
    }
    if (t < NB_SCAN) boffs[t] = s[t] - v;
}

__global__ __launch_bounds__(256) void k_scan3(int* __restrict__ rowptr,
                                               int* __restrict__ cursor,
                                               const int* __restrict__ boffs) {
    int i = blockIdx.x * 256 + threadIdx.x;
    if (i >= NN) return;
    int v = rowptr[i] + boffs[blockIdx.x];
    rowptr[i] = v;
    cursor[i] = v;
    if (i == 0) rowptr[NN] = NE;
}

__global__ __launch_bounds__(256) void k_fill(const int* __restrict__ ei,
                                              int* __restrict__ cursor,
                                              int* __restrict__ csr) {
    unsigned e = blockIdx.x * 256u + threadIdx.x;
    if (e >= NE) return;
    int s = ei[e];
    int d = ei[NE + e];
    int pos = atomicAdd(&cursor[d], 1);
    csr[pos] = s;
}

// ---------------- weight prep ----------------

__global__ __launch_bounds__(256) void k_wprep(const float* __restrict__ s0, const float* __restrict__ s1,
                                               const float* __restrict__ s2, const float* __restrict__ s3,
                                               const float* __restrict__ s4, const float* __restrict__ s5,
                                               const float* __restrict__ s6, const float* __restrict__ s7,
                                               unsigned short* __restrict__ dst) {
    const float* srcs[8] = {s0, s1, s2, s3, s4, s5, s6, s7};
    int id = blockIdx.x >> 4;                          // matrix index
    int off = ((blockIdx.x & 15) << 8) + threadIdx.x;  // 0..4095
    int k = off >> 6, n = off & 63;
    dst[id * 4096 + n * 64 + k] = f2bf(srcs[id][k * 64 + n]);
}

// w1_0 fp32 [100][64] -> bf16 transposed [64][128] (K zero-padded to 128)
__global__ __launch_bounds__(256) void k_wprep0(const float* __restrict__ w1,
                                                unsigned short* __restrict__ dst) {
    int i = blockIdx.x * 256 + threadIdx.x;  // 0..8191
    int n = i >> 7, k = i & 127;
    dst[n * 128 + k] = (k < INDIM) ? f2bf(w1[k * 64 + n]) : 0;
}

// ---------------- y0 = x @ w1_0 (no bias), MFMA, bf16 out ----------------

__global__ __launch_bounds__(256) void k_pre0(const float* __restrict__ x,
                                              const unsigned short* __restrict__ w1T,  // [64][128] bf16
                                              unsigned short* __restrict__ y) {
    __shared__ __align__(16) unsigned short xs[64 * XROW];
    int tid = threadIdx.x;
    int base = blockIdx.x * 64;
    for (int i = tid; i < 64 * 128; i += 256) {
        int r = i >> 7, c = i & 127;
        int node = base + r;
        float v = (c < INDIM && node < NN) ? x[(size_t)node * INDIM + c] : 0.f;
        xs[r * XROW + c] = f2bf(v);
    }
    __syncthreads();
    int wave = tid >> 6, lane = tid & 63;
    int quad = lane >> 4, l15 = lane & 15;
    int mt = wave;
#pragma unroll
    for (int nt = 0; nt < 4; ++nt) {
        floatx4 c = {0.f, 0.f, 0.f, 0.f};
#pragma unroll
        for (int kk = 0; kk < 4; ++kk) {
            short8 a = *(const short8*)&xs[(mt * 16 + l15) * XROW + kk * 32 + quad * 8];
            short8 b = *(const short8*)&w1T[(nt * 16 + l15) * 128 + kk * 32 + quad * 8];
            c = __builtin_amdgcn_mfma_f32_16x16x32_bf16(a, b, c, 0, 0, 0);
        }
        int col = nt * 16 + l15;
#pragma unroll
        for (int r = 0; r < 4; ++r) {
            int row = base + mt * 16 + quad * 4 + r;
            if (row < NN) y[(size_t)row * 64 + col] = f2bf(c[r]);
        }
    }
}

// ---------------- gather: t[n] = relu(y[n] + sum_{s in N(n)} y[s] + b1) ----------------
// One wave per node, NO barriers, no LDS -> full occupancy, max latency hiding.

__global__ __launch_bounds__(256) void k_gather(const unsigned short* __restrict__ y,
                                                const int* __restrict__ rowptr,
                                                const int* __restrict__ csr,
                                                const float* __restrict__ b1,
                                                unsigned short* __restrict__ t) {
    int wave = threadIdx.x >> 6, lane = threadIdx.x & 63;
    int node = blockIdx.x * 4 + wave;
    if (node >= NN) node = NN - 1;  // defensive clamp (grid is exact today)
    int nn = __builtin_amdgcn_readfirstlane(node);
    int beg = rowptr[nn], end = rowptr[nn + 1];
    float a[8];
    a[0] = bf2f(y[(size_t)nn * 64 + lane]);
#pragma unroll
    for (int j = 1; j < 8; ++j) a[j] = 0.f;
    int e = beg;
    for (; e + 16 <= end; e += 16) {
        int idx[16];
#pragma unroll
        for (int j = 0; j < 16; ++j) idx[j] = csr[e + j];
        float v[16];
#pragma unroll
        for (int j = 0; j < 16; ++j) v[j] = bf2f(y[(size_t)idx[j] * 64 + lane]);
#pragma unroll
        for (int j = 0; j < 16; ++j) a[j & 7] += v[j];
    }
    if (e + 8 <= end) {
        int idx[8];
#pragma unroll
        for (int j = 0; j < 8; ++j) idx[j] = csr[e + j];
#pragma unroll
        for (int j = 0; j < 8; ++j) a[j] += bf2f(y[(size_t)idx[j] * 64 + lane]);
        e += 8;
    }
    if (e + 4 <= end) {
        int i0 = csr[e], i1 = csr[e + 1], i2 = csr[e + 2], i3 = csr[e + 3];
        a[0] += bf2f(y[(size_t)i0 * 64 + lane]);
        a[1] += bf2f(y[(size_t)i1 * 64 + lane]);
        a[2] += bf2f(y[(size_t)i2 * 64 + lane]);
        a[3] += bf2f(y[(size_t)i3 * 64 + lane]);
        e += 4;
    }
    if (e + 2 <= end) {
        int i0 = csr[e], i1 = csr[e + 1];
        a[0] += bf2f(y[(size_t)i0 * 64 + lane]);
        a[1] += bf2f(y[(size_t)i1 * 64 + lane]);
        e += 2;
    }
    if (e < end) a[0] += bf2f(y[(size_t)csr[e] * 64 + lane]);
    float acc = ((a[0] + a[1]) + (a[2] + a[3])) + ((a[4] + a[5]) + (a[6] + a[7]));
    t[(size_t)nn * 64 + lane] = f2bf(fmaxf(acc + b1[lane], 0.f));
}

// ---------------- MFMA MLP: h=relu(t@w2+b2); jk+=h@jkw; ynext=h@wnext ----------------
// 64 nodes/block, 4 waves. A-fragments of GEMM1 come straight from global t
// (row layout == A-fragment layout, coalesced); h goes through LDS for GEMM2/3.

template <bool HAS_NEXT, bool ADD_JK>
__global__ __launch_bounds__(256) void k_mm(const unsigned short* __restrict__ t,
                                            const unsigned short* __restrict__ w2T,  // bf16 [n][k]
                                            const float* __restrict__ b2,
                                            const unsigned short* __restrict__ wnT,  // bf16 [n][k]
                                            const unsigned short* __restrict__ jkT,  // bf16 [n][k]
                                            unsigned short* __restrict__ ynext,
                                            float* __restrict__ jkacc,
                                            const float* __restrict__ jkb,
                                            const int* __restrict__ batch,
                                            float* __restrict__ g) {
    __shared__ __align__(16) unsigned short tB[64 * LROW];
    int wave = threadIdx.x >> 6, lane = threadIdx.x & 63;
    int quad = lane >> 4, l15 = lane & 15;
    int base = blockIdx.x * 64;

    // ---- GEMM1: mt = wave, nt = 0..3 ----
    int arow = base + wave * 16 + l15;
    if (arow >= NN) arow = NN - 1;  // clamp: garbage rows masked at store
    short8 a_k0 = *(const short8*)&t[(size_t)arow * 64 + quad * 8];
    short8 a_k1 = *(const short8*)&t[(size_t)arow * 64 + 32 + quad * 8];
#pragma unroll
    for (int nt = 0; nt < 4; ++nt) {
        int col = nt * 16 + l15;
        short8 b_k0 = *(const short8*)&w2T[col * 64 + quad * 8];
        short8 b_k1 = *(const short8*)&w2T[col * 64 + 32 + quad * 8];
        floatx4 c = {0.f, 0.f, 0.f, 0.f};
        c = __builtin_amdgcn_mfma_f32_16x16x32_bf16(a_k0, b_k0, c, 0, 0, 0);
        c = __builtin_amdgcn_mfma_f32_16x16x32_bf16(a_k1, b_k1, c, 0, 0, 0);
        float bb = b2[col];
#pragma unroll
        for (int r = 0; r < 4; ++r) {
            float v = fmaxf(c[r] + bb, 0.f);  // inter-layer ReLU
            tB[(wave * 16 + quad * 4 + r) * LROW + col] = f2bf(v);
        }
    }
    __syncthreads();

    // ---- GEMM2: jk = h @ jkw (+ prev)  |  GEMM3: yn = h @ wnext ----
    short8 h_k0 = *(const short8*)&tB[(wave * 16 + l15) * LROW + quad * 8];
    short8 h_k1 = *(const short8*)&tB[(wave * 16 + l15) * LROW + 32 + quad * 8];
#pragma unroll
    for (int nt = 0; nt < 4; ++nt) {
        int col = nt * 16 + l15;
        short8 j_k0 = *(const short8*)&jkT[col * 64 + quad * 8];
        short8 j_k1 = *(const short8*)&jkT[col * 64 + 32 + quad * 8];
        floatx4 cj = {0.f, 0.f, 0.f, 0.f};
        cj = __builtin_amdgcn_mfma_f32_16x16x32_bf16(h_k0, j_k0, cj, 0, 0, 0);
        cj = __builtin_amdgcn_mfma_f32_16x16x32_bf16(h_k1, j_k1, cj, 0, 0, 0);
        if (HAS_NEXT) {
            short8 w_k0 = *(const short8*)&wnT[col * 64 + quad * 8];
            short8 w_k1 = *(const short8*)&wnT[col * 64 + 32 + quad * 8];
            floatx4 cy = {0.f, 0.f, 0.f, 0.f};
            cy = __builtin_amdgcn_mfma_f32_16x16x32_bf16(h_k0, w_k0, cy, 0, 0, 0);
            cy = __builtin_amdgcn_mfma_f32_16x16x32_bf16(h_k1, w_k1, cy, 0, 0, 0);
#pragma unroll
            for (int r = 0; r < 4; ++r) {
                int row = base + wave * 16 + quad * 4 + r;
                if (row < NN) {
                    float v = cj[r] + (ADD_JK ? jkacc[(size_t)row * 64 + col] : 0.f);
                    jkacc[(size_t)row * 64 + col] = v;
                    ynext[(size_t)row * 64 + col] = f2bf(cy[r]);
                }
            }
        } else {
            float jb = jkb[col];
#pragma unroll
            for (int r = 0; r < 4; ++r) {
                int row = base + wave * 16 + quad * 4 + r;
                if (row < NN) {
                    float v = cj[r] + (ADD_JK ? jkacc[(size_t)row * 64 + col] : 0.f) + jb;
                    atomicAdd(&g[batch[row] * 64 + col], v);
                }
            }
        }
    }
}

// ---------------- final head ----------------

__global__ __launch_bounds__(64) void k_final(const float* __restrict__ g,
                                              const float* __restrict__ w1,
                                              const float* __restrict__ b1,
                                              const float* __restrict__ bng,
                                              const float* __restrict__ bnb,
                                              const float* __restrict__ bnm,
                                              const float* __restrict__ bnv,
                                              const float* __restrict__ w2,
                                              const float* __restrict__ b2,
                                              const float* __restrict__ ow,
                                              const float* __restrict__ ob,
                                              float* __restrict__ out) {
    __shared__ float gs[64];
    __shared__ float t2[64];
    __shared__ float t3[64];
    int gr = blockIdx.x, lane = threadIdx.x;
    gs[lane] = g[gr * 64 + lane];
    __syncthreads();
    float acc = b1[lane];
#pragma unroll 8
    for (int k = 0; k < 64; ++k) acc = fmaf(gs[k], w1[k * 64 + lane], acc);
    acc = (acc - bnm[lane]) * rsqrtf(bnv[lane] + 1e-5f) * bng[lane] + bnb[lane];
    t2[lane] = fmaxf(acc, 0.f);
    __syncthreads();
    float acc2 = b2[lane];
#pragma unroll 8
    for (int k = 0; k < 64; ++k) acc2 = fmaf(t2[k], w2[k * 64 + lane], acc2);
    t3[lane] = acc2;
    __syncthreads();
    if (lane < OUTD) {
        float acc3 = ob[lane];
#pragma unroll 8
        for (int k = 0; k < 64; ++k) acc3 = fmaf(t3[k], ow[k * OUTD + lane], acc3);
        out[gr * OUTD + lane] = acc3;
    }
}

extern "C" void kernel_launch(void* const* d_in, const int* in_sizes, int n_in,
                              void* d_out, int out_size, void* d_ws, size_t ws_size,
                              hipStream_t stream) {
    const float* x     = (const float*)d_in[0];
    const int*   ei    = (const int*)d_in[1];
    const int*   batch = (const int*)d_in[2];
    const float* w1_0 = (const float*)d_in[3];
    const float* b1_0 = (const float*)d_in[4];
    const float* w2_0 = (const float*)d_in[5];
    const float* b2_0 = (const float*)d_in[6];
    const float* w1_1 = (const float*)d_in[7];
    const float* b1_1 = (const float*)d_in[8];
    const float* w2_1 = (const float*)d_in[9];
    const float* b2_1 = (const float*)d_in[10];
    const float* w1_2 = (const float*)d_in[11];
    const float* b1_2 = (const float*)d_in[12];
    const float* w2_2 = (const float*)d_in[13];
    const float* b2_2 = (const float*)d_in[14];
    const float* jk_w = (const float*)d_in[15];
    const float* jk_b = (const float*)d_in[16];
    const float* ffn_w1 = (const float*)d_in[17];
    const float* ffn_b1 = (const float*)d_in[18];
    const float* bn_g = (const float*)d_in[19];
    const float* bn_b = (const float*)d_in[20];
    const float* bn_m = (const float*)d_in[21];
    const float* bn_v = (const float*)d_in[22];
    const float* ffn_w2 = (const float*)d_in[23];
    const float* ffn_b2 = (const float*)d_in[24];
    const float* out_w  = (const float*)d_in[25];
    const float* out_b  = (const float*)d_in[26];

    // workspace layout
    float* ws = (float*)d_ws;
    unsigned short* ya   = (unsigned short*)ws;        // 3.2M bf16
    unsigned short* yb   = ya + 3200000;               // 3.2M bf16
    unsigned short* tbuf = yb + 3200000;               // 3.2M bf16
    float* jkacc = (float*)(tbuf + 3200000);           // 3.2M fp32
    float* g     = jkacc + 3200000;                    // 32768
    int*   deg    = (int*)(g + 32768);                 // 50000
    int*   rowptr = deg + NN;                          // 50001
    int*   cursor = rowptr + NN + 1;                   // 50000
    int*   csr    = cursor + NN;                       // 800000
    int*   bsums  = csr + NE;                          // 196
    int*   boffs  = bsums + NB_SCAN;                   // 196
    unsigned short* wT  = (unsigned short*)(boffs + NB_SCAN + 4);  // 8 x 4096 bf16
    unsigned short* w0T = wT + 8 * 4096;                           // 64 x 128 bf16

    // ---- CSR build ----
    hipMemsetAsync(deg, 0, NN * sizeof(int), stream);
    hipMemsetAsync(g, 0, NG * 64 * sizeof(float), stream);
    k_hist<<<(NE + 255) / 256, 256, 0, stream>>>(ei, deg);
    k_scan1<<<NB_SCAN, 256, 0, stream>>>(deg, rowptr, bsums);
    k_scan2<<<1, 256, 0, stream>>>(bsums, boffs);
    k_scan3<<<NB_SCAN, 256, 0, stream>>>(rowptr, cursor, boffs);
    k_fill<<<(NE + 255) / 256, 256, 0, stream>>>(ei, cursor, csr);

    // ---- weight prep ----
    k_wprep<<<128, 256, 0, stream>>>(w2_0, w2_1, w2_2,
                                     jk_w, jk_w + 4096, jk_w + 8192,
                                     w1_1, w1_2, wT);
    k_wprep0<<<32, 256, 0, stream>>>(w1_0, w0T);

    // ---- y0 = x @ w1_0 (MFMA) ----
    k_pre0<<<(NN + 63) / 64, 256, 0, stream>>>(x, w0T, ya);

    int gblk = NN / 4;            // 12500, one wave per node
    int mblk = (NN + 63) / 64;    // 782

    // ---- layer 0 ----
    k_gather<<<gblk, 256, 0, stream>>>(ya, rowptr, csr, b1_0, tbuf);
    k_mm<true, false><<<mblk, 256, 0, stream>>>(tbuf, wT + 0 * 4096, b2_0,
                                                wT + 6 * 4096, wT + 3 * 4096,
                                                yb, jkacc, nullptr, nullptr, nullptr);
    // ---- layer 1 ----
    k_gather<<<gblk, 256, 0, stream>>>(yb, rowptr, csr, b1_1, tbuf);
    k_mm<true, true><<<mblk, 256, 0, stream>>>(tbuf, wT + 1 * 4096, b2_1,
                                               wT + 7 * 4096, wT + 4 * 4096,
                                               ya, jkacc, nullptr, nullptr, nullptr);
    // ---- layer 2: fused jk + pool ----
    k_gather<<<gblk, 256, 0, stream>>>(ya, rowptr, csr, b1_2, tbuf);
    k_mm<false, true><<<mblk, 256, 0, stream>>>(tbuf, wT + 2 * 4096, b2_2,
                                                nullptr, wT + 5 * 4096,
                                                nullptr, jkacc, jk_b, batch, g);

    // ---- head ----
    k_final<<<NG, 64, 0, stream>>>(g, ffn_w1, ffn_b1, bn_g, bn_b, bn_m, bn_v,
                                   ffn_w2, ffn_b2, out_w, out_b, (float*)d_out);
}